// Round 23
// baseline (40.595 us; speedup 1.0000x reference)
//
#include <hip/hip_runtime.h>
#include <hip/hip_bf16.h>

// Problem constants
#define IH 4096
#define IW 4096
#define KH 11
#define KW 11
#define OH (IH - KH + 1)   // 4086
#define OW (IW - KW + 1)   // 4086

// Block tile: 64x64 outputs, 4 waves (256 threads); wave wv -> rows
// 16wv..16wv+15, 4 c-tiles of 16 cols.
#define BM 64
#define BN 64
#define TROWS   74          // staged input rows (64 + 10 halo)
#define TSTRIDE 84          // bf16 row stride (proven ~free conflicts r11-r21)
#define NC4     20          // float4 chunks per staged row (80 floats)
#define NCHUNK  (TROWS * NC4)      // 1480
#define NITER   6                  // ceil(1480/256)
#define TILE_SHORTS (TROWS * TSTRIDE)  // 6216 -> 12432 B (only LDS use)

#define TILES_X 64
#define NTILE   4096

typedef short bf16x4 __attribute__((ext_vector_type(4)));
typedef short bf16x8 __attribute__((ext_vector_type(8)));
typedef float f32x4  __attribute__((ext_vector_type(4)));

__device__ __forceinline__ short f2b(float f) {
    __hip_bfloat16 h = __float2bfloat16(f);   // RNE
    return __builtin_bit_cast(short, h);
}

// ---- setup kernel (r17-r22, verified): banded-Toeplitz B in global ----
// B_kh[k][j] = w[kh][k-j] (banded), stored [kh][j][k]: lane frag = 16B chunk.
__global__ void build_bmat(const float* __restrict__ w, short* __restrict__ bm) {
    const int tid = threadIdx.x;
#pragma unroll
    for (int t = 0; t < 22; ++t) {             // 22*256 = 5632 exact
        const int idx = tid + t * 256;
        const int kh = idx >> 9;
        const int j  = (idx >> 5) & 15;
        const int k  = idx & 31;
        const int d  = k - j;
        const float val = (d >= 0 && d < KW) ? w[kh * KW + d] : 0.f;
        bm[idx] = f2b(val);
    }
}

// Depth-2 pipelined single-tile kernel. Math identical to r11-r22
// (verified): out[oy0+i][ox0+j] = sum_kh A_kh*B_kh;
// A_kh[i][k] = X[oy0+kh+i][ox0+k], B_kh[k][j] = w[kh][k-j].
// A row = lane&15, B col = lane&15, C/D col=lane&15,row=(lane>>4)*4+reg.
//
// Inner loop: 3-stage rotation (Aa/Ab/Ac). Step kh loads the frags for
// kh+2 and computes kh -> at MFMA(kh) its operands were loaded ~2 steps
// (~135 cyc of issue) earlier, covering the ~120cy ds_read latency that
// every 1-deep variant (r15/r18/r21/r22) left exposed. The compiler's
// counted lgkmcnt leaves the newest 8 reads outstanding.
__global__ __launch_bounds__(256)
void conv2d_p3(const float* __restrict__ x,
               const short* __restrict__ bg,
               const float* __restrict__ bias,
               float* __restrict__ out) {
    __shared__ short tile[TILE_SHORTS];     // 12432 B

    const int tid = threadIdx.x;
    // XCD-bijective swizzle (4096 % 8 == 0): each XCD gets 512 contiguous
    // tiles = 8 full tile rows -> halo re-reads hit the same L2.
    const int blk = (blockIdx.x & 7) * (NTILE / 8) + (blockIdx.x >> 3);
    const int gy0 = (blk >> 6) * BM;
    const int gx0 = (blk & (TILES_X - 1)) * BN;

    const int lane = tid & 63;
    const int wv   = tid >> 6;      // 0..3
    const int g    = lane >> 4;
    const int li   = lane & 15;
    const float bv = bias[0];

    // ---- B fragments -> registers, issued FIRST (their VMEM latency
    // drains under the staging below; L2-hot after warmup). Static names. ----
    const short* bp = bg + li * 32 + g * 8;
#define BLOAD(K) const bf16x8 B##K = *reinterpret_cast<const bf16x8*>(bp + (K) * 512)
    BLOAD(0); BLOAD(1); BLOAD(2); BLOAD(3); BLOAD(4); BLOAD(5);
    BLOAD(6); BLOAD(7); BLOAD(8); BLOAD(9); BLOAD(10);
#undef BLOAD

    // ---- Stage input tile as bf16 (r18-verified; conflicts ~0.9e6) ----
#pragma unroll
    for (int it = 0; it < NITER; ++it) {
        const int i = tid + it * 256;
        if (i < NCHUNK) {
            const int r  = i / NC4;
            const int c4 = i - r * NC4;
            const int gy = gy0 + r;
            const int gx = gx0 + c4 * 4;
            float4 v = make_float4(0.f, 0.f, 0.f, 0.f);
            if (gy < IH && gx + 3 < IW) {
                v = *reinterpret_cast<const float4*>(x + (size_t)gy * IW + gx);
            }
            bf16x4 b = { f2b(v.x), f2b(v.y), f2b(v.z), f2b(v.w) };
            *reinterpret_cast<bf16x4*>(&tile[r * TSTRIDE + c4 * 4]) = b;
        }
    }
    __syncthreads();

    // ---- Depth-2 pipelined compute ----
    f32x4 acc[4] = {};
    const short* ap = &tile[(16 * wv + li) * TSTRIDE + g * 8];

    bf16x8 Aa[4], Ab[4], Ac[4];
#define LOADA(A, ROW) do {                                                   \
        const short* p_ = ap + (ROW) * TSTRIDE;                              \
        _Pragma("unroll")                                                    \
        for (int c = 0; c < 4; ++c) {                                        \
            bf16x4 lo = *reinterpret_cast<const bf16x4*>(p_ + c * 16);       \
            bf16x4 hi = *reinterpret_cast<const bf16x4*>(p_ + c * 16 + 4);   \
            A[c] = __builtin_shufflevector(lo, hi, 0, 1, 2, 3, 4, 5, 6, 7);  \
        }                                                                    \
    } while (0)
#define MFMA4(A, B) do {                                                     \
        _Pragma("unroll")                                                    \
        for (int c = 0; c < 4; ++c)                                          \
            acc[c] = __builtin_amdgcn_mfma_f32_16x16x32_bf16(A[c], B,        \
                                                             acc[c], 0, 0, 0); \
    } while (0)
    // Step kh: load stage (kh+2)%3 with row kh+2, compute stage kh%3.
    // sched_barrier stops cross-step hoisting (balloon guard, r9/r21);
    // the 2-step lead is already explicit so it costs no overlap.
#define STEP(CUR, NXT, ROW, B) LOADA(NXT, ROW); MFMA4(CUR, B); \
        __builtin_amdgcn_sched_barrier(0)

    LOADA(Aa, 0);
    LOADA(Ab, 1);
    STEP(Aa, Ac, 2, B0);
    STEP(Ab, Aa, 3, B1);
    STEP(Ac, Ab, 4, B2);
    STEP(Aa, Ac, 5, B3);
    STEP(Ab, Aa, 6, B4);
    STEP(Ac, Ab, 7, B5);
    STEP(Aa, Ac, 8, B6);
    STEP(Ab, Aa, 9, B7);
    STEP(Ac, Ab, 10, B8);
    MFMA4(Aa, B9);
    MFMA4(Ab, B10);

#undef STEP
#undef MFMA4
#undef LOADA

    // ---- Write back ----
#pragma unroll
    for (int c = 0; c < 4; ++c) {
        const int ox = gx0 + c * 16 + li;
        if (ox < OW) {
#pragma unroll
            for (int r = 0; r < 4; ++r) {
                const int oy = gy0 + wv * 16 + g * 4 + r;
                if (oy < OH) {
                    out[(size_t)oy * OW + ox] = acc[c][r] + bv;
                }
            }
        }
    }
}

extern "C" void kernel_launch(void* const* d_in, const int* in_sizes, int n_in,
                              void* d_out, int out_size, void* d_ws, size_t ws_size,
                              hipStream_t stream) {
    const float* x    = (const float*)d_in[0];
    const float* w    = (const float*)d_in[1];
    const float* bias = (const float*)d_in[2];
    float* out        = (float*)d_out;
    short* bm         = (short*)d_ws;        // 11264 B of scratch

    build_bmat<<<dim3(1), dim3(256), 0, stream>>>(w, bm);

    dim3 grid(NTILE);     // 4096 single-tile blocks
    dim3 block(256);
    conv2d_p3<<<grid, block, 0, stream>>>(x, bm, bias, out);
}